// Round 12
// baseline (293.092 us; speedup 1.0000x reference)
//
#include <hip/hip_runtime.h>

#define N_TEX 65536
#define C 16
#define U 4194304
#define ILP 4
#define SPIN_CYCLES 500000ll   // ~210us @2.4GHz, ~330us @1.5GHz

typedef float    f32x4 __attribute__((ext_vector_type(4)));
typedef int      i32x4 __attribute__((ext_vector_type(4)));
typedef _Float16 f16x4 __attribute__((ext_vector_type(4)));

// ---------------------------------------------------------------------------
// Convert fp32 texture (4 MiB) -> fp16 (2 MiB) in d_ws.
// ---------------------------------------------------------------------------
__global__ __launch_bounds__(256) void convert_kernel(
    const f32x4* __restrict__ in, f16x4* __restrict__ out16)
{
    const int i = blockIdx.x * 256 + threadIdx.x;
    f32x4 v = __builtin_nontemporal_load(&in[i]);
    f16x4 h;
    h.x = (_Float16)v.x; h.y = (_Float16)v.y;
    h.z = (_Float16)v.z; h.w = (_Float16)v.w;
    out16[i] = h;
}

// ---------------------------------------------------------------------------
// Cheap warm kernel (exact R7 version, the best performer): 2,048 blocks,
// XCD-aware, single touch of param slices + full texture per XCD.
// ---------------------------------------------------------------------------
__global__ __launch_bounds__(256) void warm_kernel(
    const i32x4* __restrict__ texv, const f32x4* __restrict__ paramv)
{
    const int b = blockIdx.x;
    const int t = threadIdx.x;
    const int i = t >> 5;
    const int g = t & 31;
    const int s = (b & 7) + 8 * ((b >> 3) * 8 + i);
    const int k0 = g >> 4;
    const int m  = g & 15;
    f32x4 p0 = paramv[s * 16 + m + k0 * 262144];
    f32x4 p1 = paramv[s * 16 + m + (k0 + 2) * 262144];
    const int cbase = (b >> 3) * 512 + t * 2;
    i32x4 t0 = texv[cbase];
    i32x4 t1 = texv[cbase + 1];
    asm volatile("" :: "v"(p0), "v"(p1), "v"(t0), "v"(t1));
}

// ---------------------------------------------------------------------------
// DVFS spacer: ONE block, 64 threads, spins on the shader clock for
// SPIN_CYCLES with no memory traffic and near-zero power. Content-neutral:
// touches no caches. If the following sampler speeds up, the D1 anomaly was
// power/clock recovery, not cache state.
// ---------------------------------------------------------------------------
__global__ __launch_bounds__(64) void spacer_kernel()
{
    const long long t0 = (long long)clock64();
    while (((long long)clock64() - t0) < SPIN_CYCLES) { }
}

// ---------------------------------------------------------------------------
// Sampler: EXACT R7 kernel -- fp16 texture, 4 lanes/sample, ILP=4,
// nontemporal param loads + output stores.
// ---------------------------------------------------------------------------
__global__ __launch_bounds__(256) void sampler1d_kernel(
    const f16x4* __restrict__ tex16, const float* __restrict__ param,
    f32x4* __restrict__ out)
{
    const int NT  = (U * 4) / ILP;
    const int tid = blockIdx.x * 256 + threadIdx.x;
    const int q   = tid & 3;

    float p[ILP];
#pragma unroll
    for (int k = 0; k < ILP; ++k)
        p[k] = __builtin_nontemporal_load(&param[(tid + k * NT) >> 2]);

    float w[ILP];
    f16x4 a[ILP], b[ILP];
#pragma unroll
    for (int k = 0; k < ILP; ++k) {
        const float t = p[k] * (float)(N_TEX - 1);
        float f = floorf(t);
        f = fminf(fmaxf(f, 0.0f), (float)(N_TEX - 1));
        const int i0 = (int)f;
        const int i1 = min(i0 + 1, N_TEX - 1);
        w[k] = t - f;
        a[k] = tex16[i0 * 4 + q];
        b[k] = tex16[i1 * 4 + q];
    }

#pragma unroll
    for (int k = 0; k < ILP; ++k) {
        const float wk = w[k], iw = 1.0f - wk;
        f32x4 r;
        r.x = (float)a[k].x * iw + (float)b[k].x * wk;
        r.y = (float)a[k].y * iw + (float)b[k].y * wk;
        r.z = (float)a[k].z * iw + (float)b[k].z * wk;
        r.w = (float)a[k].w * iw + (float)b[k].w * wk;
        __builtin_nontemporal_store(r, &out[tid + k * NT]);
    }
}

extern "C" void kernel_launch(void* const* d_in, const int* in_sizes, int n_in,
                              void* d_out, int out_size, void* d_ws, size_t ws_size,
                              hipStream_t stream) {
    const f32x4* tex32 = (const f32x4*)d_in[0];
    const float* param = (const float*)d_in[1];
    f32x4*       out   = (f32x4*)d_out;
    f16x4*       tex16 = (f16x4*)d_ws;     // 2 MiB scratch

    const int total_thr = (U * 4) / ILP;   // 4,194,304 -> 16,384 blocks

    convert_kernel<<<(N_TEX * C / 4) / 256, 256, 0, stream>>>(tex32, tex16);
    warm_kernel<<<2048, 256, 0, stream>>>((const i32x4*)tex16, (const f32x4*)param);
    spacer_kernel<<<1, 64, 0, stream>>>();
    sampler1d_kernel<<<total_thr / 256, 256, 0, stream>>>(tex16, param, out);
}

// Round 13
// 93.217 us; speedup vs baseline: 3.1442x; 3.1442x over previous
//
#include <hip/hip_runtime.h>

#define N_TEX 65536
#define C 16
#define U 4194304
#define TPB 256
#define NBLK 2048                      // 8 blocks/CU nominal
#define NTHREADS (NBLK * TPB)          // 524,288
#define UNITS (U * 4)                  // 16,777,216 quad-units
#define BATCH 4
#define NBATCH (UNITS / NTHREADS / BATCH)  // 8

typedef float    f32x4 __attribute__((ext_vector_type(4)));
typedef int      i32x4 __attribute__((ext_vector_type(4)));
typedef _Float16 f16x4 __attribute__((ext_vector_type(4)));

// ---------------------------------------------------------------------------
// Convert fp32 texture (4 MiB) -> fp16 (2 MiB) in d_ws.
// ---------------------------------------------------------------------------
__global__ __launch_bounds__(256) void convert_kernel(
    const f32x4* __restrict__ in, f16x4* __restrict__ out16)
{
    const int i = blockIdx.x * 256 + threadIdx.x;
    f32x4 v = __builtin_nontemporal_load(&in[i]);
    f16x4 h;
    h.x = (_Float16)v.x; h.y = (_Float16)v.y;
    h.z = (_Float16)v.z; h.w = (_Float16)v.w;
    out16[i] = h;
}

// ---------------------------------------------------------------------------
// Warm kernel (R7 version, proven +12us): single-touch param + texture.
// ---------------------------------------------------------------------------
__global__ __launch_bounds__(256) void warm_kernel(
    const i32x4* __restrict__ texv, const f32x4* __restrict__ paramv)
{
    const int b = blockIdx.x;
    const int t = threadIdx.x;
    const int i = t >> 5;
    const int g = t & 31;
    const int s = (b & 7) + 8 * ((b >> 3) * 8 + i);
    const int k0 = g >> 4;
    const int m  = g & 15;
    f32x4 p0 = paramv[s * 16 + m + k0 * 262144];
    f32x4 p1 = paramv[s * 16 + m + (k0 + 2) * 262144];
    const int cbase = (b >> 3) * 512 + t * 2;
    i32x4 t0 = texv[cbase];
    i32x4 t1 = texv[cbase + 1];
    asm volatile("" :: "v"(p0), "v"(p1), "v"(t0), "v"(t1));
}

// ---------------------------------------------------------------------------
// Persistent software-pipelined sampler. Each thread owns 32 quad-units
// (8 batches x 4). Steady-state per iteration j:
//   issue gathers for batch j+1  (param already arrived)
//   issue param loads for batch j+2
//   wait gathers j (partial vmcnt), interpolate, nt-store batch j
//   sched_barrier(0)  -- keep iterations from re-bunching
// So every wave always has param loads + 8 gathers + stores outstanding
// simultaneously -> HBM-read, L2-read, HBM-write engines all busy at once,
// instead of the grid marching through separate phase-bursts.
// ---------------------------------------------------------------------------
__global__ __launch_bounds__(256) void sampler1d_kernel(
    const f16x4* __restrict__ tex16, const float* __restrict__ param,
    f32x4* __restrict__ out)
{
    const int tid = blockIdx.x * TPB + threadIdx.x;
    const int q   = tid & 3;   // NTHREADS % 4 == 0 -> q constant per thread

    float p[2][BATCH];
    float w[2][BATCH];
    f16x4 ga[2][BATCH], gb[2][BATCH];

    // prologue: params for batches 0,1; gathers for batch 0
#pragma unroll
    for (int k = 0; k < BATCH; ++k)
        p[0][k] = __builtin_nontemporal_load(&param[(tid + k * NTHREADS) >> 2]);
#pragma unroll
    for (int k = 0; k < BATCH; ++k)
        p[1][k] = __builtin_nontemporal_load(&param[(tid + (BATCH + k) * NTHREADS) >> 2]);
#pragma unroll
    for (int k = 0; k < BATCH; ++k) {
        const float t = p[0][k] * (float)(N_TEX - 1);
        const float f = fminf(fmaxf(floorf(t), 0.0f), (float)(N_TEX - 1));
        const int i0 = (int)f;
        const int i1 = min(i0 + 1, N_TEX - 1);
        w[0][k]  = t - f;
        ga[0][k] = tex16[i0 * 4 + q];
        gb[0][k] = tex16[i1 * 4 + q];
    }

#pragma unroll
    for (int j = 0; j < NBATCH; ++j) {
        const int cur = j & 1, nxt = (j + 1) & 1;

        if (j + 1 < NBATCH) {           // issue gathers for batch j+1
#pragma unroll
            for (int k = 0; k < BATCH; ++k) {
                const float t = p[nxt][k] * (float)(N_TEX - 1);
                const float f = fminf(fmaxf(floorf(t), 0.0f), (float)(N_TEX - 1));
                const int i0 = (int)f;
                const int i1 = min(i0 + 1, N_TEX - 1);
                w[nxt][k]  = t - f;
                ga[nxt][k] = tex16[i0 * 4 + q];
                gb[nxt][k] = tex16[i1 * 4 + q];
            }
        }
        if (j + 2 < NBATCH) {           // issue param loads for batch j+2
#pragma unroll
            for (int k = 0; k < BATCH; ++k)
                p[cur][k] = __builtin_nontemporal_load(
                    &param[(tid + ((j + 2) * BATCH + k) * NTHREADS) >> 2]);
        }
        // consume batch j
#pragma unroll
        for (int k = 0; k < BATCH; ++k) {
            const float wk = w[cur][k], iw = 1.0f - wk;
            f32x4 r;
            r.x = (float)ga[cur][k].x * iw + (float)gb[cur][k].x * wk;
            r.y = (float)ga[cur][k].y * iw + (float)gb[cur][k].y * wk;
            r.z = (float)ga[cur][k].z * iw + (float)gb[cur][k].z * wk;
            r.w = (float)ga[cur][k].w * iw + (float)gb[cur][k].w * wk;
            __builtin_nontemporal_store(r, &out[tid + (j * BATCH + k) * NTHREADS]);
        }
        __builtin_amdgcn_sched_barrier(0);
    }
}

extern "C" void kernel_launch(void* const* d_in, const int* in_sizes, int n_in,
                              void* d_out, int out_size, void* d_ws, size_t ws_size,
                              hipStream_t stream) {
    const f32x4* tex32 = (const f32x4*)d_in[0];
    const float* param = (const float*)d_in[1];
    f32x4*       out   = (f32x4*)d_out;
    f16x4*       tex16 = (f16x4*)d_ws;     // 2 MiB scratch

    convert_kernel<<<(N_TEX * C / 4) / 256, 256, 0, stream>>>(tex32, tex16);
    warm_kernel<<<2048, 256, 0, stream>>>((const i32x4*)tex16, (const f32x4*)param);
    sampler1d_kernel<<<NBLK, TPB, 0, stream>>>(tex16, param, out);
}